// Round 12
// baseline (62.738 us; speedup 1.0000x reference)
//
#include <hip/hip_runtime.h>
#include <float.h>
#include <math.h>

#define BB 32
#define SS 1024
#define DD 512
#define NCH 32          // softmax chunks per batch (32 rows each)
#define CROWS 32
#define RW 8            // rows per wave
#define NXCH 32         // xsum chunks per batch (32 rows each)

typedef float f32x4 __attribute__((ext_vector_type(4)));

__device__ __forceinline__ float wave_reduce_add(float v) {
    #pragma unroll
    for (int m = 32; m >= 1; m >>= 1) v += __shfl_xor(v, m, 64);
    return v;
}

// ---------------- K1: xsum partials straight from x (read-only, f32x4) ----------------
// grid (NXCH, BB), 256 threads; block sums a 32-row chunk. Thread owns cols
// col4..col4+3 with row parity p; 16 iterations of stride 2 rows.
__global__ __launch_bounds__(256) void k_xsumx(
    const float* __restrict__ x, float* __restrict__ xsum_part)
{
    int ch = blockIdx.x, b = blockIdx.y, tid = threadIdx.x;
    int p = tid >> 7, col4 = (tid & 127) * 4;
    size_t base = ((size_t)b * SS + ch * 32 + p) * DD + col4;
    f32x4 acc = {0.f, 0.f, 0.f, 0.f};
    #pragma unroll 8
    for (int it = 0; it < 16; ++it)
        acc += *(const f32x4*)(x + base + (size_t)it * 2 * DD);
    // two row-parities per chunk: reduce via direct store of per-parity partial
    // chunk partial index: ch, with parity folded by atomic-free split store
    *(f32x4*)(xsum_part + (((size_t)b * NXCH + ch) * 2 + p) * DD + col4) = acc;
}

// ---------------- K2: ks partials: ks_part[dc][b][e] ----------------
// grid (8 dc, 2 eb, 4 bg), 256 threads. (R5-proven; sums 64 parity-chunks)
__global__ __launch_bounds__(256) void k_ks(
    const float* __restrict__ xsum_part, const float* __restrict__ Wk,
    float* __restrict__ ks_part)
{
    __shared__ float xs[8][64];
    int dc = blockIdx.x, eb = blockIdx.y, bg = blockIdx.z;
    int tid = threadIdx.x;
    int e = eb * 256 + tid;
    #pragma unroll
    for (int k = 0; k < 2; ++k) {
        int i = tid + k * 256;
        int bi = i >> 6, dl = i & 63;
        int b = bg * 8 + bi, d = dc * 64 + dl;
        float v = 0.f;
        #pragma unroll 8
        for (int scc = 0; scc < NXCH * 2; ++scc)
            v += xsum_part[((size_t)b * NXCH * 2 + scc) * DD + d];
        xs[bi][dl] = v;
    }
    __syncthreads();
    float acc[8] = {0,0,0,0,0,0,0,0};
    #pragma unroll 8
    for (int dl = 0; dl < 64; ++dl) {
        float w = Wk[(size_t)(dc * 64 + dl) * DD + e];
        #pragma unroll
        for (int bi = 0; bi < 8; ++bi) acc[bi] += xs[bi][dl] * w;
    }
    #pragma unroll
    for (int bi = 0; bi < 8; ++bi) {
        int b = bg * 8 + bi;
        ks_part[((size_t)dc * BB + b) * DD + e] = acc[bi];
    }
}

// ---------------- K3: v partials: v_part[ec][b][d] ----------------
// grid (8 ec, 2 db, 4 bg), 256 threads. (R5-proven)
__global__ __launch_bounds__(256) void k_v(
    const float* __restrict__ ks_part, const float* __restrict__ Wq,
    const float* __restrict__ bk, float* __restrict__ v_part)
{
    __shared__ float wq_lds[256 * 65];
    __shared__ float ks_lds[8][64];
    int ec = blockIdx.x, db = blockIdx.y, bg = blockIdx.z;
    int tid = threadIdx.x;
    #pragma unroll
    for (int k = 0; k < 2; ++k) {
        int i = tid + k * 256;
        int bi = i >> 6, el = i & 63;
        int b = bg * 8 + bi, e = ec * 64 + el;
        float val = (float)SS * bk[e];
        #pragma unroll
        for (int dcc = 0; dcc < 8; ++dcc)
            val += ks_part[((size_t)dcc * BB + b) * DD + e];
        ks_lds[bi][el] = val;
    }
    #pragma unroll
    for (int it = 0; it < 16; ++it) {
        int idx = tid + it * 256;
        int rowd = idx >> 4, col4 = idx & 15;
        f32x4 wv = *(const f32x4*)(Wq + (size_t)(db * 256 + rowd) * DD + ec * 64 + col4 * 4);
        float* dst = &wq_lds[rowd * 65 + col4 * 4];
        dst[0] = wv.x; dst[1] = wv.y; dst[2] = wv.z; dst[3] = wv.w;
    }
    __syncthreads();
    float acc[8] = {0,0,0,0,0,0,0,0};
    #pragma unroll 8
    for (int el = 0; el < 64; ++el) {
        float wq = wq_lds[tid * 65 + el];
        #pragma unroll
        for (int bi = 0; bi < 8; ++bi) acc[bi] += ks_lds[bi][el] * wq;
    }
    int d = db * 256 + tid;
    #pragma unroll
    for (int bi = 0; bi < 8; ++bi) {
        int b = bg * 8 + bi;
        v_part[((size_t)ec * BB + b) * DD + d] = acc[bi];
    }
}

// ---------------- K4: SINGLE fused pass: copy + BOTH score branches ----------------
// grid (BB, NCH), 256 threads = 4 waves x 8 rows. Plain (cached) stores.
__global__ __launch_bounds__(256) void k_pass1full(
    const float* __restrict__ x, const float* __restrict__ w_score,
    const float* __restrict__ v_part, const int* __restrict__ x_len,
    float* __restrict__ out_x,
    float* __restrict__ lP, float* __restrict__ lm, float* __restrict__ lS,
    float* __restrict__ gP, float* __restrict__ gm, float* __restrict__ gS)
{
    __shared__ float v_lds[DD];
    __shared__ float red_l[4][DD];
    __shared__ float red_g[4][DD];
    __shared__ float msl[4], Ssl[4], msg[4], Ssg[4];
    int b = blockIdx.x, sc = blockIdx.y;
    int wave = threadIdx.x >> 6, lane = threadIdx.x & 63, tid = threadIdx.x;
    int len = x_len[b];
    int s0 = sc * CROWS + wave * RW;
    size_t base = ((size_t)b * SS + s0) * DD;

    #pragma unroll
    for (int i = 0; i < 2; ++i) {
        int d = tid + i * 256;
        float vv = 0.f;
        #pragma unroll
        for (int ec = 0; ec < 8; ++ec) vv += v_part[((size_t)ec * BB + b) * DD + d];
        v_lds[d] = vv;
    }
    __syncthreads();
    const f32x4* vr = (const f32x4*)v_lds;
    f32x4 v0 = vr[lane], v1 = vr[lane + 64];
    const f32x4* wr = (const f32x4*)w_score;
    f32x4 w0 = wr[lane], w1 = wr[lane + 64];

    f32x4 a[RW][2];
    #pragma unroll
    for (int r = 0; r < RW; ++r) {
        const f32x4* xr = (const f32x4*)(x + base + (size_t)r * DD);
        a[r][0] = xr[lane];
        a[r][1] = xr[lane + 64];
    }
    #pragma unroll
    for (int r = 0; r < RW; ++r) {
        f32x4* orow = (f32x4*)(out_x + base + (size_t)r * DD);
        orow[lane]      = a[r][0];
        orow[lane + 64] = a[r][1];
    }
    float pl[RW], pg[RW];
    #pragma unroll
    for (int r = 0; r < RW; ++r) {
        f32x4 t0 = a[r][0] * w0 + a[r][1] * w1;
        pl[r] = t0.x + t0.y + t0.z + t0.w;
        f32x4 u0 = a[r][0] * v0 + a[r][1] * v1;
        pg[r] = u0.x + u0.y + u0.z + u0.w;
    }
    #pragma unroll
    for (int r = 0; r < RW; ++r) {
        pl[r] = wave_reduce_add(pl[r]);
        pg[r] = wave_reduce_add(pg[r]) * 0.04419417382415922f;
    }
    float mwl = -FLT_MAX, mwg = -FLT_MAX;
    #pragma unroll
    for (int r = 0; r < RW; ++r) {
        if (s0 + r < len) {
            mwl = fmaxf(mwl, pl[r]);
            mwg = fmaxf(mwg, pg[r]);
        }
    }
    float Swl = 0.f, Swg = 0.f;
    f32x4 cl0 = {0,0,0,0}, cl1 = {0,0,0,0}, cg0 = {0,0,0,0}, cg1 = {0,0,0,0};
    #pragma unroll
    for (int r = 0; r < RW; ++r) {
        bool valid = (s0 + r) < len;
        float wl = valid ? __expf(pl[r] - mwl) : 0.f;
        float wg = valid ? __expf(pg[r] - mwg) : 0.f;
        Swl += wl; Swg += wg;
        cl0 += wl * a[r][0]; cl1 += wl * a[r][1];
        cg0 += wg * a[r][0]; cg1 += wg * a[r][1];
    }
    f32x4* rl = (f32x4*)red_l[wave];
    f32x4* rg = (f32x4*)red_g[wave];
    rl[lane] = cl0; rl[lane + 64] = cl1;
    rg[lane] = cg0; rg[lane + 64] = cg1;
    if (lane == 0) { msl[wave] = mwl; Ssl[wave] = Swl; msg[wave] = mwg; Ssg[wave] = Swg; }
    __syncthreads();
    float mcl = fmaxf(fmaxf(msl[0], msl[1]), fmaxf(msl[2], msl[3]));
    float mcg = fmaxf(fmaxf(msg[0], msg[1]), fmaxf(msg[2], msg[3]));
    float el0 = __expf(msl[0] - mcl), el1 = __expf(msl[1] - mcl);
    float el2 = __expf(msl[2] - mcl), el3 = __expf(msl[3] - mcl);
    float eg0 = __expf(msg[0] - mcg), eg1 = __expf(msg[1] - mcg);
    float eg2 = __expf(msg[2] - mcg), eg3 = __expf(msg[3] - mcg);
    #pragma unroll
    for (int i = 0; i < 2; ++i) {
        int d = tid + i * 256;
        size_t off = ((size_t)b * NCH + sc) * DD + d;
        lP[off] = red_l[0][d]*el0 + red_l[1][d]*el1 + red_l[2][d]*el2 + red_l[3][d]*el3;
        gP[off] = red_g[0][d]*eg0 + red_g[1][d]*eg1 + red_g[2][d]*eg2 + red_g[3][d]*eg3;
    }
    if (tid == 0) {
        lm[b * NCH + sc] = mcl;
        lS[b * NCH + sc] = Ssl[0]*el0 + Ssl[1]*el1 + Ssl[2]*el2 + Ssl[3]*el3;
        gm[b * NCH + sc] = mcg;
        gS[b * NCH + sc] = Ssg[0]*eg0 + Ssg[1]*eg1 + Ssg[2]*eg2 + Ssg[3]*eg3;
    }
}

// ---------------- K5: merge chunk partials, beta-combine ----------------
__global__ __launch_bounds__(512) void k_combine(
    const float* __restrict__ lP, const float* __restrict__ lm, const float* __restrict__ lS,
    const float* __restrict__ gP, const float* __restrict__ gm, const float* __restrict__ gS,
    const int* __restrict__ slot_idx, const float* __restrict__ beta_raw,
    float* __restrict__ out_c)
{
    int b = blockIdx.x, d = threadIdx.x;
    float Ml = -FLT_MAX, Mg = -FLT_MAX;
    #pragma unroll 8
    for (int c = 0; c < NCH; ++c) {
        Ml = fmaxf(Ml, lm[b * NCH + c]);
        Mg = fmaxf(Mg, gm[b * NCH + c]);
    }
    float Sl = 0.f, Pl = 0.f, Sg = 0.f, Pg = 0.f;
    #pragma unroll 4
    for (int c = 0; c < NCH; ++c) {
        float wl = __expf(lm[b * NCH + c] - Ml);
        float wg = __expf(gm[b * NCH + c] - Mg);
        Sl += lS[b * NCH + c] * wl;
        Sg += gS[b * NCH + c] * wg;
        Pl += lP[((size_t)b * NCH + c) * DD + d] * wl;
        Pg += gP[((size_t)b * NCH + c) * DD + d] * wg;
    }
    float br = beta_raw[slot_idx[0]];
    float beta = 1.f / (1.f + __expf(-br));
    out_c[b * DD + d] = beta * Pl / Sl + (1.f - beta) * Pg / Sg;
}

extern "C" void kernel_launch(void* const* d_in, const int* in_sizes, int n_in,
                              void* d_out, int out_size, void* d_ws, size_t ws_size,
                              hipStream_t stream) {
    const float* x        = (const float*)d_in[0];
    const int*   x_len    = (const int*)d_in[1];
    const int*   slot_idx = (const int*)d_in[2];
    const float* w_score  = (const float*)d_in[3];
    // d_in[4] = b_score (softmax shift-invariant, unused)
    const float* Wq       = (const float*)d_in[5];
    // d_in[6] = bq (only affects shift-invariant t, unused)
    const float* Wk       = (const float*)d_in[7];
    const float* bk       = (const float*)d_in[8];
    const float* beta_raw = (const float*)d_in[9];

    float* out   = (float*)d_out;
    float* out_x = out;                           // [B,S,D]
    float* out_c = out + (size_t)BB * SS * DD;    // [B,D]

    float* ws = (float*)d_ws;
    float* xsum_part = ws;                        // 32*64*512 = 1048576
    float* lP        = ws + 1048576;              // 524288
    float* gP        = ws + 1572864;              // 524288
    float* ks_part   = ws + 2097152;              // 131072
    float* v_part    = ws + 2228224;              // 131072
    float* lm        = ws + 2359296;              // 1024
    float* lS        = ws + 2360320;              // 1024
    float* gm        = ws + 2361344;              // 1024
    float* gS        = ws + 2362368;              // 1024

    k_xsumx<<<dim3(NXCH, BB), 256, 0, stream>>>(x, xsum_part);
    k_ks<<<dim3(8, 2, 4), 256, 0, stream>>>(xsum_part, Wk, ks_part);
    k_v<<<dim3(8, 2, 4), 256, 0, stream>>>(ks_part, Wq, bk, v_part);
    k_pass1full<<<dim3(BB, NCH), 256, 0, stream>>>(x, w_score, v_part, x_len, out_x,
                                                   lP, lm, lS, gP, gm, gS);
    k_combine<<<BB, 512, 0, stream>>>(lP, lm, lS, gP, gm, gS, slot_idx, beta_raw, out_c);
}

// Round 13
// 61.677 us; speedup vs baseline: 1.0172x; 1.0172x over previous
//
#include <hip/hip_runtime.h>
#include <float.h>
#include <math.h>

#define BB 32
#define SS 1024
#define DD 512
#define NCH 32          // softmax chunks per batch (32 rows each)
#define CROWS 32
#define RW 8            // rows per wave
#define NXCH 16         // xsum chunks per batch (64 rows each)

typedef float f32x4 __attribute__((ext_vector_type(4)));
typedef float f32x2 __attribute__((ext_vector_type(2)));

__device__ __forceinline__ float wave_reduce_add(float v) {
    #pragma unroll
    for (int m = 32; m >= 1; m >>= 1) v += __shfl_xor(v, m, 64);
    return v;
}

// ---------------- K1: xsum partials straight from x (read-only) ----------------
// grid (NXCH, BB), 256 threads; each block streams 64 contiguous rows. (R9-exact)
__global__ __launch_bounds__(256) void k_xsumx(
    const float* __restrict__ x, float* __restrict__ xsum_part)
{
    int sc = blockIdx.x, b = blockIdx.y, tid = threadIdx.x;
    const float* xb = x + ((size_t)b * SS + sc * 64) * DD + tid * 2;
    f32x2 acc = {0.f, 0.f};
    #pragma unroll 8
    for (int r = 0; r < 64; ++r)
        acc += *(const f32x2*)(xb + (size_t)r * DD);
    *(f32x2*)(xsum_part + ((size_t)b * NXCH + sc) * DD + tid * 2) = acc;
}

// ---------------- K2: fused ks + v partials (short-loop phases) ----------------
// grid (8 ec, 2 db, 4 bg), 256 threads.
// Phase A: ks[b][e] for the 64-e slice, d-split across 4 waves (128 d each),
//          LDS 4-way reduce. Phase B: R5-proven LDS-tiled Wq dot.
__global__ __launch_bounds__(256) void k_kv(
    const float* __restrict__ xsum_part, const float* __restrict__ Wk,
    const float* __restrict__ Wq, const float* __restrict__ bk,
    float* __restrict__ v_part)
{
    __shared__ float tile[256 * 65];   // phase B Wq tile; phase A aliases xs+ksp
    __shared__ float ksl[8][64];
    float* xs  = tile;                 // [8][512] = 16 KB
    float* ksp = tile + 8 * DD;        // [4][8][64] = 8 KB
    int ec = blockIdx.x, db = blockIdx.y, bg = blockIdx.z;
    int tid = threadIdx.x;

    // stage xs[bi][d] = full xsum for 8 batches (reduce 16 chunks, L2-resident)
    #pragma unroll
    for (int i = 0; i < 16; ++i) {
        int idx = tid + i * 256;
        int bi = idx >> 9, d = idx & 511;
        int b = bg * 8 + bi;
        float v = 0.f;
        #pragma unroll
        for (int c = 0; c < NXCH; ++c)
            v += xsum_part[((size_t)b * NXCH + c) * DD + d];
        xs[bi * DD + d] = v;
    }
    __syncthreads();

    // phase A: thread (el = tid&63, dg = tid>>6) covers 128 d's
    int el = tid & 63, dg = tid >> 6;
    int e = ec * 64 + el;
    float pk[8] = {0,0,0,0,0,0,0,0};
    #pragma unroll 8
    for (int dd = 0; dd < 128; ++dd) {
        int d = dg * 128 + dd;
        float w = Wk[(size_t)d * DD + e];          // lane-coalesced over e
        #pragma unroll
        for (int bi = 0; bi < 8; ++bi)
            pk[bi] += xs[bi * DD + d] * w;          // wave-uniform addr: broadcast
    }
    #pragma unroll
    for (int bi = 0; bi < 8; ++bi)
        ksp[(dg * 8 + bi) * 64 + el] = pk[bi];
    __syncthreads();
    // 4-way reduce + bias -> ksl
    #pragma unroll
    for (int k = 0; k < 2; ++k) {
        int idx = tid + k * 256;
        int bi = idx >> 6, e2 = idx & 63;
        float s = ksp[(0 * 8 + bi) * 64 + e2] + ksp[(1 * 8 + bi) * 64 + e2]
                + ksp[(2 * 8 + bi) * 64 + e2] + ksp[(3 * 8 + bi) * 64 + e2];
        ksl[bi][e2] = s + (float)SS * bk[ec * 64 + e2];
    }
    __syncthreads();

    // phase B: stage Wq [256 d of db-half][64 e of ec-slice] into tile (padded)
    int d0 = db * 256;
    #pragma unroll
    for (int it = 0; it < 16; ++it) {
        int idx = tid + it * 256;
        int rowd = idx >> 4, col4 = idx & 15;
        f32x4 wv = *(const f32x4*)(Wq + (size_t)(d0 + rowd) * DD + ec * 64 + col4 * 4);
        float* dst = &tile[rowd * 65 + col4 * 4];
        dst[0] = wv.x; dst[1] = wv.y; dst[2] = wv.z; dst[3] = wv.w;
    }
    __syncthreads();
    float acc[8] = {0,0,0,0,0,0,0,0};
    #pragma unroll 8
    for (int e2 = 0; e2 < 64; ++e2) {
        float wq = tile[tid * 65 + e2];
        #pragma unroll
        for (int bi = 0; bi < 8; ++bi) acc[bi] += ksl[bi][e2] * wq;
    }
    #pragma unroll
    for (int bi = 0; bi < 8; ++bi) {
        int b = bg * 8 + bi;
        v_part[((size_t)ec * BB + b) * DD + d0 + tid] = acc[bi];
    }
}

// ---------------- K3: SINGLE fused pass: copy + BOTH score branches (R9-exact) ----
// grid (BB, NCH), 256 threads = 4 waves x 8 rows.
__global__ __launch_bounds__(256) void k_pass1full(
    const float* __restrict__ x, const float* __restrict__ w_score,
    const float* __restrict__ v_part, const int* __restrict__ x_len,
    float* __restrict__ out_x,
    float* __restrict__ lP, float* __restrict__ lm, float* __restrict__ lS,
    float* __restrict__ gP, float* __restrict__ gm, float* __restrict__ gS)
{
    __shared__ float v_lds[DD];
    __shared__ float red_l[4][DD];
    __shared__ float red_g[4][DD];
    __shared__ float msl[4], Ssl[4], msg[4], Ssg[4];
    int b = blockIdx.x, sc = blockIdx.y;
    int wave = threadIdx.x >> 6, lane = threadIdx.x & 63, tid = threadIdx.x;
    int len = x_len[b];
    int s0 = sc * CROWS + wave * RW;
    size_t base = ((size_t)b * SS + s0) * DD;

    #pragma unroll
    for (int i = 0; i < 2; ++i) {
        int d = tid + i * 256;
        float vv = 0.f;
        #pragma unroll
        for (int ec = 0; ec < 8; ++ec) vv += v_part[((size_t)ec * BB + b) * DD + d];
        v_lds[d] = vv;
    }
    __syncthreads();
    const f32x4* vr = (const f32x4*)v_lds;
    f32x4 v0 = vr[lane], v1 = vr[lane + 64];
    const f32x4* wr = (const f32x4*)w_score;
    f32x4 w0 = wr[lane], w1 = wr[lane + 64];

    f32x4 a[RW][2];
    #pragma unroll
    for (int r = 0; r < RW; ++r) {
        const f32x4* xr = (const f32x4*)(x + base + (size_t)r * DD);
        a[r][0] = xr[lane];
        a[r][1] = xr[lane + 64];
    }
    #pragma unroll
    for (int r = 0; r < RW; ++r) {
        f32x4* orow = (f32x4*)(out_x + base + (size_t)r * DD);
        __builtin_nontemporal_store(a[r][0], &orow[lane]);
        __builtin_nontemporal_store(a[r][1], &orow[lane + 64]);
    }
    float pl[RW], pg[RW];
    #pragma unroll
    for (int r = 0; r < RW; ++r) {
        f32x4 t0 = a[r][0] * w0 + a[r][1] * w1;
        pl[r] = t0.x + t0.y + t0.z + t0.w;
        f32x4 u0 = a[r][0] * v0 + a[r][1] * v1;
        pg[r] = u0.x + u0.y + u0.z + u0.w;
    }
    #pragma unroll
    for (int r = 0; r < RW; ++r) {
        pl[r] = wave_reduce_add(pl[r]);
        pg[r] = wave_reduce_add(pg[r]) * 0.04419417382415922f;
    }
    float mwl = -FLT_MAX, mwg = -FLT_MAX;
    #pragma unroll
    for (int r = 0; r < RW; ++r) {
        if (s0 + r < len) {
            mwl = fmaxf(mwl, pl[r]);
            mwg = fmaxf(mwg, pg[r]);
        }
    }
    float Swl = 0.f, Swg = 0.f;
    f32x4 cl0 = {0,0,0,0}, cl1 = {0,0,0,0}, cg0 = {0,0,0,0}, cg1 = {0,0,0,0};
    #pragma unroll
    for (int r = 0; r < RW; ++r) {
        bool valid = (s0 + r) < len;
        float wl = valid ? __expf(pl[r] - mwl) : 0.f;
        float wg = valid ? __expf(pg[r] - mwg) : 0.f;
        Swl += wl; Swg += wg;
        cl0 += wl * a[r][0]; cl1 += wl * a[r][1];
        cg0 += wg * a[r][0]; cg1 += wg * a[r][1];
    }
    f32x4* rl = (f32x4*)red_l[wave];
    f32x4* rg = (f32x4*)red_g[wave];
    rl[lane] = cl0; rl[lane + 64] = cl1;
    rg[lane] = cg0; rg[lane + 64] = cg1;
    if (lane == 0) { msl[wave] = mwl; Ssl[wave] = Swl; msg[wave] = mwg; Ssg[wave] = Swg; }
    __syncthreads();
    float mcl = fmaxf(fmaxf(msl[0], msl[1]), fmaxf(msl[2], msl[3]));
    float mcg = fmaxf(fmaxf(msg[0], msg[1]), fmaxf(msg[2], msg[3]));
    float el0 = __expf(msl[0] - mcl), el1 = __expf(msl[1] - mcl);
    float el2 = __expf(msl[2] - mcl), el3 = __expf(msl[3] - mcl);
    float eg0 = __expf(msg[0] - mcg), eg1 = __expf(msg[1] - mcg);
    float eg2 = __expf(msg[2] - mcg), eg3 = __expf(msg[3] - mcg);
    #pragma unroll
    for (int i = 0; i < 2; ++i) {
        int d = tid + i * 256;
        size_t off = ((size_t)b * NCH + sc) * DD + d;
        lP[off] = red_l[0][d]*el0 + red_l[1][d]*el1 + red_l[2][d]*el2 + red_l[3][d]*el3;
        gP[off] = red_g[0][d]*eg0 + red_g[1][d]*eg1 + red_g[2][d]*eg2 + red_g[3][d]*eg3;
    }
    if (tid == 0) {
        lm[b * NCH + sc] = mcl;
        lS[b * NCH + sc] = Ssl[0]*el0 + Ssl[1]*el1 + Ssl[2]*el2 + Ssl[3]*el3;
        gm[b * NCH + sc] = mcg;
        gS[b * NCH + sc] = Ssg[0]*eg0 + Ssg[1]*eg1 + Ssg[2]*eg2 + Ssg[3]*eg3;
    }
}

// ---------------- K4: merge chunk partials, beta-combine (R9-exact) ----------------
__global__ __launch_bounds__(512) void k_combine(
    const float* __restrict__ lP, const float* __restrict__ lm, const float* __restrict__ lS,
    const float* __restrict__ gP, const float* __restrict__ gm, const float* __restrict__ gS,
    const int* __restrict__ slot_idx, const float* __restrict__ beta_raw,
    float* __restrict__ out_c)
{
    int b = blockIdx.x, d = threadIdx.x;
    float Ml = -FLT_MAX, Mg = -FLT_MAX;
    #pragma unroll 8
    for (int c = 0; c < NCH; ++c) {
        Ml = fmaxf(Ml, lm[b * NCH + c]);
        Mg = fmaxf(Mg, gm[b * NCH + c]);
    }
    float Sl = 0.f, Pl = 0.f, Sg = 0.f, Pg = 0.f;
    #pragma unroll 4
    for (int c = 0; c < NCH; ++c) {
        float wl = __expf(lm[b * NCH + c] - Ml);
        float wg = __expf(gm[b * NCH + c] - Mg);
        Sl += lS[b * NCH + c] * wl;
        Sg += gS[b * NCH + c] * wg;
        Pl += lP[((size_t)b * NCH + c) * DD + d] * wl;
        Pg += gP[((size_t)b * NCH + c) * DD + d] * wg;
    }
    float br = beta_raw[slot_idx[0]];
    float beta = 1.f / (1.f + __expf(-br));
    out_c[b * DD + d] = beta * Pl / Sl + (1.f - beta) * Pg / Sg;
}

extern "C" void kernel_launch(void* const* d_in, const int* in_sizes, int n_in,
                              void* d_out, int out_size, void* d_ws, size_t ws_size,
                              hipStream_t stream) {
    const float* x        = (const float*)d_in[0];
    const int*   x_len    = (const int*)d_in[1];
    const int*   slot_idx = (const int*)d_in[2];
    const float* w_score  = (const float*)d_in[3];
    // d_in[4] = b_score (softmax shift-invariant, unused)
    const float* Wq       = (const float*)d_in[5];
    // d_in[6] = bq (only affects shift-invariant t, unused)
    const float* Wk       = (const float*)d_in[7];
    const float* bk       = (const float*)d_in[8];
    const float* beta_raw = (const float*)d_in[9];

    float* out   = (float*)d_out;
    float* out_x = out;                           // [B,S,D]
    float* out_c = out + (size_t)BB * SS * DD;    // [B,D]

    float* ws = (float*)d_ws;
    float* xsum_part = ws;                        // 32*16*512 = 262144
    float* lP        = ws + 262144;               // 524288
    float* gP        = ws + 786432;               // 524288
    float* v_part    = ws + 1310720;              // 8*32*512 = 131072
    float* lm        = ws + 1441792;              // 1024
    float* lS        = ws + 1442816;              // 1024
    float* gm        = ws + 1443840;              // 1024
    float* gS        = ws + 1444864;              // 1024

    k_xsumx<<<dim3(NXCH, BB), 256, 0, stream>>>(x, xsum_part);
    k_kv<<<dim3(8, 2, 4), 256, 0, stream>>>(xsum_part, Wk, Wq, bk, v_part);
    k_pass1full<<<dim3(BB, NCH), 256, 0, stream>>>(x, w_score, v_part, x_len, out_x,
                                                   lP, lm, lS, gP, gm, gS);
    k_combine<<<BB, 512, 0, stream>>>(lP, lm, lS, gP, gm, gS, slot_idx, beta_raw, out_c);
}

// Round 14
// 57.558 us; speedup vs baseline: 1.0900x; 1.0716x over previous
//
#include <hip/hip_runtime.h>
#include <float.h>
#include <math.h>

#define BB 32
#define SS 1024
#define DD 512
#define NCH 32          // softmax chunks per batch (32 rows each)
#define CROWS 32
#define RW 8            // rows per wave
#define NXCH 16         // xsum chunks per batch (64 rows each)

typedef float f32x4 __attribute__((ext_vector_type(4)));
typedef float f32x2 __attribute__((ext_vector_type(2)));

__device__ __forceinline__ float wave_reduce_add(float v) {
    #pragma unroll
    for (int m = 32; m >= 1; m >>= 1) v += __shfl_xor(v, m, 64);
    return v;
}

// ---------------- K1: xsum partials straight from x ----------------
// grid (NXCH, BB), 256 threads; each block streams 64 contiguous rows.
__global__ __launch_bounds__(256) void k_xsumx(
    const float* __restrict__ x, float* __restrict__ xsum_part)
{
    int sc = blockIdx.x, b = blockIdx.y, tid = threadIdx.x;
    const float* xb = x + ((size_t)b * SS + sc * 64) * DD + tid * 2;
    f32x2 acc = {0.f, 0.f};
    #pragma unroll 8
    for (int r = 0; r < 64; ++r)
        acc += *(const f32x2*)(xb + (size_t)r * DD);
    *(f32x2*)(xsum_part + ((size_t)b * NXCH + sc) * DD + tid * 2) = acc;
}

// ---------------- K2: ks partials: ks_part[dc][b][e] ----------------
// grid (8 dc, 2 eb, 4 bg), 256 threads. Inner loop 64-deep, coalesced Wk rows.
__global__ __launch_bounds__(256) void k_ks(
    const float* __restrict__ xsum_part, const float* __restrict__ Wk,
    float* __restrict__ ks_part)
{
    __shared__ float xs[8][64];
    int dc = blockIdx.x, eb = blockIdx.y, bg = blockIdx.z;
    int tid = threadIdx.x;
    int e = eb * 256 + tid;
    #pragma unroll
    for (int k = 0; k < 2; ++k) {
        int i = tid + k * 256;
        int bi = i >> 6, dl = i & 63;
        int b = bg * 8 + bi, d = dc * 64 + dl;
        float v = 0.f;
        #pragma unroll
        for (int scc = 0; scc < NXCH; ++scc)
            v += xsum_part[((size_t)b * NXCH + scc) * DD + d];
        xs[bi][dl] = v;
    }
    __syncthreads();
    float acc[8] = {0,0,0,0,0,0,0,0};
    #pragma unroll 8
    for (int dl = 0; dl < 64; ++dl) {
        float w = Wk[(size_t)(dc * 64 + dl) * DD + e];
        #pragma unroll
        for (int bi = 0; bi < 8; ++bi) acc[bi] += xs[bi][dl] * w;
    }
    #pragma unroll
    for (int bi = 0; bi < 8; ++bi) {
        int b = bg * 8 + bi;
        ks_part[((size_t)dc * BB + b) * DD + e] = acc[bi];
    }
}

// ---------------- K3: v partials: v_part[ec][b][d] ----------------
// grid (8 ec, 2 db, 4 bg), 256 threads. (R5-proven k_v)
__global__ __launch_bounds__(256) void k_v(
    const float* __restrict__ ks_part, const float* __restrict__ Wq,
    const float* __restrict__ bk, float* __restrict__ v_part)
{
    __shared__ float wq_lds[256 * 65];
    __shared__ float ks_lds[8][64];
    int ec = blockIdx.x, db = blockIdx.y, bg = blockIdx.z;
    int tid = threadIdx.x;
    #pragma unroll
    for (int k = 0; k < 2; ++k) {
        int i = tid + k * 256;
        int bi = i >> 6, el = i & 63;
        int b = bg * 8 + bi, e = ec * 64 + el;
        float val = (float)SS * bk[e];
        #pragma unroll
        for (int dcc = 0; dcc < 8; ++dcc)
            val += ks_part[((size_t)dcc * BB + b) * DD + e];
        ks_lds[bi][el] = val;
    }
    #pragma unroll
    for (int it = 0; it < 16; ++it) {
        int idx = tid + it * 256;
        int rowd = idx >> 4, col4 = idx & 15;
        f32x4 wv = *(const f32x4*)(Wq + (size_t)(db * 256 + rowd) * DD + ec * 64 + col4 * 4);
        float* dst = &wq_lds[rowd * 65 + col4 * 4];
        dst[0] = wv.x; dst[1] = wv.y; dst[2] = wv.z; dst[3] = wv.w;
    }
    __syncthreads();
    float acc[8] = {0,0,0,0,0,0,0,0};
    #pragma unroll 8
    for (int el = 0; el < 64; ++el) {
        float wq = wq_lds[tid * 65 + el];
        #pragma unroll
        for (int bi = 0; bi < 8; ++bi) acc[bi] += ks_lds[bi][el] * wq;
    }
    int d = db * 256 + tid;
    #pragma unroll
    for (int bi = 0; bi < 8; ++bi) {
        int b = bg * 8 + bi;
        v_part[((size_t)ec * BB + b) * DD + d] = acc[bi];
    }
}

// ---------------- K4: SINGLE pass over x: copy + BOTH score branches ----------------
// grid (BB, NCH), 256 threads = 4 waves x 8 rows.
__global__ __launch_bounds__(256) void k_pass1full(
    const float* __restrict__ x, const float* __restrict__ w_score,
    const float* __restrict__ v_part, const int* __restrict__ x_len,
    float* __restrict__ out_x,
    float* __restrict__ lP, float* __restrict__ lm, float* __restrict__ lS,
    float* __restrict__ gP, float* __restrict__ gm, float* __restrict__ gS)
{
    __shared__ float v_lds[DD];
    __shared__ float red_l[4][DD];
    __shared__ float red_g[4][DD];
    __shared__ float msl[4], Ssl[4], msg[4], Ssg[4];
    int b = blockIdx.x, sc = blockIdx.y;
    int wave = threadIdx.x >> 6, lane = threadIdx.x & 63, tid = threadIdx.x;
    int len = x_len[b];
    int s0 = sc * CROWS + wave * RW;
    size_t base = ((size_t)b * SS + s0) * DD;

    // reduce v_part (L2-resident) into LDS
    #pragma unroll
    for (int i = 0; i < 2; ++i) {
        int d = tid + i * 256;
        float vv = 0.f;
        #pragma unroll
        for (int ec = 0; ec < 8; ++ec) vv += v_part[((size_t)ec * BB + b) * DD + d];
        v_lds[d] = vv;
    }
    __syncthreads();
    const f32x4* vr = (const f32x4*)v_lds;
    f32x4 v0 = vr[lane], v1 = vr[lane + 64];
    const f32x4* wr = (const f32x4*)w_score;
    f32x4 w0 = wr[lane], w1 = wr[lane + 64];

    f32x4 a[RW][2];
    #pragma unroll
    for (int r = 0; r < RW; ++r) {
        const f32x4* xr = (const f32x4*)(x + base + (size_t)r * DD);
        a[r][0] = xr[lane];
        a[r][1] = xr[lane + 64];
    }
    #pragma unroll
    for (int r = 0; r < RW; ++r) {
        f32x4* orow = (f32x4*)(out_x + base + (size_t)r * DD);
        __builtin_nontemporal_store(a[r][0], &orow[lane]);
        __builtin_nontemporal_store(a[r][1], &orow[lane + 64]);
    }
    float pl[RW], pg[RW];
    #pragma unroll
    for (int r = 0; r < RW; ++r) {
        f32x4 t0 = a[r][0] * w0 + a[r][1] * w1;
        pl[r] = t0.x + t0.y + t0.z + t0.w;
        f32x4 u0 = a[r][0] * v0 + a[r][1] * v1;
        pg[r] = u0.x + u0.y + u0.z + u0.w;
    }
    #pragma unroll
    for (int r = 0; r < RW; ++r) {
        pl[r] = wave_reduce_add(pl[r]);
        pg[r] = wave_reduce_add(pg[r]) * 0.04419417382415922f;
    }
    float mwl = -FLT_MAX, mwg = -FLT_MAX;
    #pragma unroll
    for (int r = 0; r < RW; ++r) {
        if (s0 + r < len) {
            mwl = fmaxf(mwl, pl[r]);
            mwg = fmaxf(mwg, pg[r]);
        }
    }
    float Swl = 0.f, Swg = 0.f;
    f32x4 cl0 = {0,0,0,0}, cl1 = {0,0,0,0}, cg0 = {0,0,0,0}, cg1 = {0,0,0,0};
    #pragma unroll
    for (int r = 0; r < RW; ++r) {
        bool valid = (s0 + r) < len;
        float wl = valid ? __expf(pl[r] - mwl) : 0.f;
        float wg = valid ? __expf(pg[r] - mwg) : 0.f;
        Swl += wl; Swg += wg;
        cl0 += wl * a[r][0]; cl1 += wl * a[r][1];
        cg0 += wg * a[r][0]; cg1 += wg * a[r][1];
    }
    f32x4* rl = (f32x4*)red_l[wave];
    f32x4* rg = (f32x4*)red_g[wave];
    rl[lane] = cl0; rl[lane + 64] = cl1;
    rg[lane] = cg0; rg[lane + 64] = cg1;
    if (lane == 0) { msl[wave] = mwl; Ssl[wave] = Swl; msg[wave] = mwg; Ssg[wave] = Swg; }
    __syncthreads();
    float mcl = fmaxf(fmaxf(msl[0], msl[1]), fmaxf(msl[2], msl[3]));
    float mcg = fmaxf(fmaxf(msg[0], msg[1]), fmaxf(msg[2], msg[3]));
    float el0 = __expf(msl[0] - mcl), el1 = __expf(msl[1] - mcl);
    float el2 = __expf(msl[2] - mcl), el3 = __expf(msl[3] - mcl);
    float eg0 = __expf(msg[0] - mcg), eg1 = __expf(msg[1] - mcg);
    float eg2 = __expf(msg[2] - mcg), eg3 = __expf(msg[3] - mcg);
    #pragma unroll
    for (int i = 0; i < 2; ++i) {
        int d = tid + i * 256;
        size_t off = ((size_t)b * NCH + sc) * DD + d;
        lP[off] = red_l[0][d]*el0 + red_l[1][d]*el1 + red_l[2][d]*el2 + red_l[3][d]*el3;
        gP[off] = red_g[0][d]*eg0 + red_g[1][d]*eg1 + red_g[2][d]*eg2 + red_g[3][d]*eg3;
    }
    if (tid == 0) {
        lm[b * NCH + sc] = mcl;
        lS[b * NCH + sc] = Ssl[0]*el0 + Ssl[1]*el1 + Ssl[2]*el2 + Ssl[3]*el3;
        gm[b * NCH + sc] = mcg;
        gS[b * NCH + sc] = Ssg[0]*eg0 + Ssg[1]*eg1 + Ssg[2]*eg2 + Ssg[3]*eg3;
    }
}

// ---------------- K5: merge chunk partials, beta-combine ----------------
__global__ __launch_bounds__(512) void k_combine(
    const float* __restrict__ lP, const float* __restrict__ lm, const float* __restrict__ lS,
    const float* __restrict__ gP, const float* __restrict__ gm, const float* __restrict__ gS,
    const int* __restrict__ slot_idx, const float* __restrict__ beta_raw,
    float* __restrict__ out_c)
{
    int b = blockIdx.x, d = threadIdx.x;
    float Ml = -FLT_MAX, Mg = -FLT_MAX;
    #pragma unroll 8
    for (int c = 0; c < NCH; ++c) {
        Ml = fmaxf(Ml, lm[b * NCH + c]);
        Mg = fmaxf(Mg, gm[b * NCH + c]);
    }
    float Sl = 0.f, Pl = 0.f, Sg = 0.f, Pg = 0.f;
    #pragma unroll 4
    for (int c = 0; c < NCH; ++c) {
        float wl = __expf(lm[b * NCH + c] - Ml);
        float wg = __expf(gm[b * NCH + c] - Mg);
        Sl += lS[b * NCH + c] * wl;
        Sg += gS[b * NCH + c] * wg;
        Pl += lP[((size_t)b * NCH + c) * DD + d] * wl;
        Pg += gP[((size_t)b * NCH + c) * DD + d] * wg;
    }
    float br = beta_raw[slot_idx[0]];
    float beta = 1.f / (1.f + __expf(-br));
    out_c[b * DD + d] = beta * Pl / Sl + (1.f - beta) * Pg / Sg;
}

extern "C" void kernel_launch(void* const* d_in, const int* in_sizes, int n_in,
                              void* d_out, int out_size, void* d_ws, size_t ws_size,
                              hipStream_t stream) {
    const float* x        = (const float*)d_in[0];
    const int*   x_len    = (const int*)d_in[1];
    const int*   slot_idx = (const int*)d_in[2];
    const float* w_score  = (const float*)d_in[3];
    // d_in[4] = b_score (softmax shift-invariant, unused)
    const float* Wq       = (const float*)d_in[5];
    // d_in[6] = bq (only affects shift-invariant t, unused)
    const float* Wk       = (const float*)d_in[7];
    const float* bk       = (const float*)d_in[8];
    const float* beta_raw = (const float*)d_in[9];

    float* out   = (float*)d_out;
    float* out_x = out;                           // [B,S,D]
    float* out_c = out + (size_t)BB * SS * DD;    // [B,D]

    float* ws = (float*)d_ws;
    float* xsum_part = ws;                        // 32*16*512 = 262144
    float* ks_part   = ws + 262144;               // 8*32*512  = 131072
    float* v_part    = ws + 393216;               // 8*32*512  = 131072
    float* lP        = ws + 524288;               // 524288
    float* gP        = ws + 1048576;              // 524288
    float* lm        = ws + 1572864;              // 1024
    float* lS        = ws + 1573888;              // 1024
    float* gm        = ws + 1574912;              // 1024
    float* gS        = ws + 1575936;              // 1024

    k_xsumx<<<dim3(NXCH, BB), 256, 0, stream>>>(x, xsum_part);
    k_ks<<<dim3(8, 2, 4), 256, 0, stream>>>(xsum_part, Wk, ks_part);
    k_v<<<dim3(8, 2, 4), 256, 0, stream>>>(ks_part, Wq, bk, v_part);
    k_pass1full<<<dim3(BB, NCH), 256, 0, stream>>>(x, w_score, v_part, x_len, out_x,
                                                   lP, lm, lS, gP, gm, gS);
    k_combine<<<BB, 512, 0, stream>>>(lP, lm, lS, gP, gm, gS, slot_idx, beta_raw, out_c);
}